// Round 1
// 240.300 us; speedup vs baseline: 1.0989x; 1.0989x over previous
//
#include <hip/hip_runtime.h>

#define B_ 16
#define N_ 16384
#define S_ 4096
#define K_ 16
#define TS 32
#define DOUT 128

typedef __bf16 bf16;
typedef __attribute__((ext_vector_type(8))) __bf16 bf16x8;
typedef __attribute__((ext_vector_type(4))) float f32x4;

__device__ __forceinline__ unsigned pack2(float a, float b) {
  unsigned short ua = __builtin_bit_cast(unsigned short, (bf16)a);
  unsigned short ub = __builtin_bit_cast(unsigned short, (bf16)b);
  return (unsigned)ua | ((unsigned)ub << 16);
}

template <int NCH>
__device__ __forceinline__ void ln_leaky(const float* h, const float* g, const float* e, float* o) {
  float m = 0.f;
#pragma unroll
  for (int j = 0; j < NCH; ++j) m += h[j];
  m *= (1.0f / NCH);
  float v = 0.f;
#pragma unroll
  for (int j = 0; j < NCH; ++j) { float d = h[j] - m; v += d * d; }
  v *= (1.0f / NCH);
  float inv = rsqrtf(v + 1e-5f);
#pragma unroll
  for (int j = 0; j < NCH; ++j) {
    float t = (h[j] - m) * inv * g[j] + e[j];
    o[j] = t < 0.f ? 0.2f * t : t;
  }
}

__global__ void k_fill(float* out, float v) {
  out[blockIdx.x * 256 + threadIdx.x] = v;
}

// points [B,64,N] f32 -> ptT [B,N,64] bf16 (unchanged from r6).
__global__ __launch_bounds__(256) void k_transpose(const float* __restrict__ pts,
                                                   bf16* __restrict__ pt) {
  int b = blockIdx.y;
  int n0 = blockIdx.x * 256;
  int tc = threadIdx.x & 7;
  int tn = threadIdx.x >> 3;
  const float* src = pts + (size_t)b * 64 * N_ + (size_t)(tc * 8) * N_ + n0 + tn * 8;
  float4 row[8][2];
#pragma unroll
  for (int i = 0; i < 8; ++i) {
    row[i][0] = *(const float4*)(src + (size_t)i * N_);
    row[i][1] = *(const float4*)(src + (size_t)i * N_ + 4);
  }
  bf16* dst = pt + ((size_t)b * N_ + n0 + tn * 8) * 64 + tc * 8;
#pragma unroll
  for (int j = 0; j < 8; ++j) {
    float v[8];
#pragma unroll
    for (int i = 0; i < 8; ++i) {
      float4 q = row[i][j >> 2];
      v[i] = ((j & 3) == 0) ? q.x : ((j & 3) == 1) ? q.y : ((j & 3) == 2) ? q.z : q.w;
    }
    *(uint4*)(dst + (size_t)j * 64) = make_uint4(
        pack2(v[0], v[1]), pack2(v[2], v[3]), pack2(v[4], v[5]), pack2(v[6], v[7]));
  }
}

// wl [1072,128] f32 -> wlF: B-fragment-order bf16 so a wave's MFMA B-frag is one
// coalesced 1KB load. Element for (tile t, kkg, lane L, j):
//   wl_k = kkg*32 + (L>>4)*8 + j   (zero for wl_k >= 1072)
//   n    = t*16 + (L&15)
// wlF short index = ((t*34 + kkg)*64 + L)*8 + j.  Size 8*34*64*8 = 139264 shorts.
__global__ void k_wlf(const float* __restrict__ wl, bf16* __restrict__ wlF) {
  int blk = blockIdx.x;            // t*34 + kkg
  int kkg = blk % 34;
  int t = blk / 34;
  int tid = threadIdx.x;
  int L = tid >> 2, jp = (tid & 3) * 2;
  int k = kkg * 32 + ((L >> 4) << 3) + jp;
  int n = t * 16 + (L & 15);
  float v0 = (k < 1072) ? wl[(size_t)k * 128 + n] : 0.f;
  float v1 = (k + 1 < 1072) ? wl[(size_t)(k + 1) * 128 + n] : 0.f;
  ((unsigned*)wlF)[(size_t)blk * 256 + tid] = pack2(v0, v1);
}

__global__ __launch_bounds__(256, 4) void k_main(
    const float* __restrict__ xyz, const float* __restrict__ nxyz,
    const int* __restrict__ nnidx,
    const bf16* __restrict__ ptT, const bf16* __restrict__ wlF,
    const float* __restrict__ w0p, const float* __restrict__ b0p,
    const float* __restrict__ g0p, const float* __restrict__ be0p,
    const float* __restrict__ w1p, const float* __restrict__ b1p,
    const float* __restrict__ g1p, const float* __restrict__ be1p,
    const float* __restrict__ w2p, const float* __restrict__ b2p,
    const float* __restrict__ g2p, const float* __restrict__ be2p,
    const float* __restrict__ blp, const float* __restrict__ glp,
    const float* __restrict__ belp, float* __restrict__ out) {
  // LDS (35.4 KB total -> 4 blocks/CU):
  __shared__ __align__(16) bf16 w_sT[32 * 264];   // [s][m*16+k], s-stride 264 (pad 8)
  __shared__ __align__(16) bf16 feat2[32 * 144];  // [s][c*16+k], s-stride 144 (pad 16)
  __shared__ __align__(16) bf16 aggA[32 * 136];   // [s][c*16+m], s-stride 136 (pad 8)
  __shared__ float nx[3][TS];
  __shared__ float ln_m[TS], ln_i[TS];

  const int tid = threadIdx.x;
  // XCD-affinity swizzle: workgroups round-robin across 8 XCDs (xcd = L % 8).
  // Map so XCD x owns batches {2x, 2x+1}: its concurrent gather footprint is one
  // 2 MB ptT slice (fits 4 MB per-XCD L2) instead of all 16 slices streaming
  // through every XCD (which cost 8 XCD x 33.5 MB = 268 MB of HBM refetch).
  // Bijective: L = ((b&1)*128 + stile)*8 + (b>>1).
  const unsigned Lwg = blockIdx.y * 128u + blockIdx.x;
  const int xcd = (int)(Lwg & 7u);
  const int li = (int)(Lwg >> 3);          // 0..255 within XCD
  const int b = xcd * 2 + (li >> 7);       // batch
  const int s0 = (li & 127) * TS;          // s-tile origin
  const size_t ibase = ((size_t)b * S_ + s0) * K_;

  if (tid < 96) {
    int c = tid >> 5, j = tid & 31;
    nx[c][j] = nxyz[((size_t)b * 3 + c) * S_ + s0 + j];
  }
  // gather-phase indices (this thread's two points), register-resident
  const int ig0 = nnidx[ibase + tid];
  const int ig1 = nnidx[ibase + tid + 256];
  // weightnet-phase indices (points 2*tid, 2*tid+1)
  const int iw0 = nnidx[ibase + 2 * tid];
  const int iw1 = nnidx[ibase + 2 * tid + 1];
  __syncthreads();

  // ---- WeightNet: points p0=2*tid (s=tid>>3, k0=2*(tid&7)) and p0+1 ----
  float xa[3], xb[3];
  const int ws = tid >> 3;        // s for weightnet outputs
  const int wk = (tid & 7) * 2;   // even k
  {
#pragma unroll
    for (int c = 0; c < 3; ++c) {
      float nv = nx[c][ws];
      xa[c] = xyz[((size_t)b * 3 + c) * N_ + iw0] - nv;
      xb[c] = xyz[((size_t)b * 3 + c) * N_ + iw1] - nv;
    }
    float ya[8], yb[8];
    {
      float h0[8], h1[8];
#pragma unroll
      for (int j = 0; j < 8; ++j) {
        h0[j] = b0p[j] + xa[0] * w0p[j] + xa[1] * w0p[8 + j] + xa[2] * w0p[16 + j];
        h1[j] = b0p[j] + xb[0] * w0p[j] + xb[1] * w0p[8 + j] + xb[2] * w0p[16 + j];
      }
      ln_leaky<8>(h0, g0p, be0p, ya);
      ln_leaky<8>(h1, g0p, be0p, yb);
    }
    {
      float h0[8], h1[8];
#pragma unroll
      for (int j = 0; j < 8; ++j) { h0[j] = b1p[j]; h1[j] = b1p[j]; }
#pragma unroll
      for (int i = 0; i < 8; ++i) {
#pragma unroll
        for (int j = 0; j < 8; ++j) {
          float w = w1p[i * 8 + j];
          h0[j] += ya[i] * w; h1[j] += yb[i] * w;
        }
      }
      ln_leaky<8>(h0, g1p, be1p, ya);
      ln_leaky<8>(h1, g1p, be1p, yb);
    }
    {
      float h0[16], h1[16];
#pragma unroll
      for (int j = 0; j < 16; ++j) { h0[j] = b2p[j]; h1[j] = b2p[j]; }
#pragma unroll
      for (int i = 0; i < 8; ++i) {
#pragma unroll
        for (int j = 0; j < 16; ++j) {
          float w = w2p[i * 16 + j];
          h0[j] += ya[i] * w; h1[j] += yb[i] * w;
        }
      }
      float z0[16], z1[16];
      ln_leaky<16>(h0, g2p, be2p, z0);
      ln_leaky<16>(h1, g2p, be2p, z1);
      // w_sT[s][m*16+k]: pack both k's (wk, wk+1) into one b32 per m
      bf16* wp = w_sT + ws * 264 + wk;
#pragma unroll
      for (int m = 0; m < 16; ++m)
        *(unsigned*)(wp + m * 16) = pack2(z0[m], z1[m]);
    }
  }

  // ---- MFMA wave geometry ----
  const int lane = tid & 63;
  const int wv = tid >> 6;
  const int rt = wv & 1;        // main-GEMM row tile
  const int cw = wv >> 1;       // main-GEMM col pair
  const int l16 = lane & 15;
  const int q = lane >> 4;
  // agg-MFMA lane roles
  const bool adiag = ((((lane >> 5) ^ (lane >> 3)) & 1) == 0);
  const int aoff = ((lane >> 3) & 1) * 144 + (lane & 7) * 16 + (q & 1) * 8;
  const int boff = (lane >> 5) * 264 + l16 * 16 + (q & 1) * 8;
  const int soff = (lane >> 5) * 136 + (q & 1) * 64 + l16;  // + r*16
  f32x4 a00 = {0.f, 0.f, 0.f, 0.f};
  f32x4 a01 = a00, a10 = a00, a11 = a00;
  const f32x4 zc = a00;

  const bf16* ptB = ptT + (size_t)b * N_ * 64;
  const int gs0 = tid >> 4, gk = tid & 15;  // gather slots: s=gs0 / gs0+16, k=gk

  uint4 pf0, pf1;
  pf0 = *(const uint4*)(ptB + (size_t)ig0 * 64);
  pf1 = *(const uint4*)(ptB + (size_t)ig1 * 64);

  for (int ch = 0; ch < 9; ++ch) {
    const int nkk = (ch < 8) ? 4 : 2;
    __syncthreads();  // (A) prev agg done with feat2/w_sT reads; prev main done with aggA
    // stage feat2[s][c*16+k] for this chunk
    if (ch < 8) {
      bf16 t0[8], t1[8];
      *(uint4*)t0 = pf0;
      *(uint4*)t1 = pf1;
      bf16* f0 = feat2 + gs0 * 144 + gk;
      bf16* f1 = feat2 + (gs0 + 16) * 144 + gk;
#pragma unroll
      for (int c = 0; c < 8; ++c) {
        f0[c * 16] = t0[c];
        f1[c * 16] = t1[c];
      }
    } else {
      // gxn channels (3 real + 5 zero), packed pairs (wk, wk+1)
      bf16* fp = feat2 + ws * 144 + wk;
      *(unsigned*)(fp + 0 * 16) = pack2(xa[0], xb[0]);
      *(unsigned*)(fp + 1 * 16) = pack2(xa[1], xb[1]);
      *(unsigned*)(fp + 2 * 16) = pack2(xa[2], xb[2]);
#pragma unroll
      for (int c = 3; c < 8; ++c) *(unsigned*)(fp + c * 16) = 0u;
    }
    __syncthreads();  // (B)
    if (ch < 8) {  // prefetch next chunk's gather
      int nc = ch + 1;
      if (nc < 8) {
        pf0 = *(const uint4*)(ptB + (size_t)ig0 * 64 + nc * 8);
        pf1 = *(const uint4*)(ptB + (size_t)ig1 * 64 + nc * 8);
      }
    }
    // agg via block-diagonal MFMA: 2 s per MFMA, 4 MFMAs per wave
#pragma unroll
    for (int pp = 0; pp < 4; ++pp) {
      int s2 = (wv * 4 + pp) * 2;
      uint4 au = *(const uint4*)(feat2 + s2 * 144 + aoff);
      if (!adiag) au = make_uint4(0u, 0u, 0u, 0u);
      bf16x8 af = __builtin_bit_cast(bf16x8, au);
      bf16x8 bw = *(const bf16x8*)(w_sT + s2 * 264 + boff);
      f32x4 d = __builtin_amdgcn_mfma_f32_16x16x32_bf16(af, bw, zc, 0, 0, 0);
      bf16* cp = aggA + s2 * 136 + soff;
#pragma unroll
      for (int r = 0; r < 4; ++r) cp[r * 16] = (bf16)d[r];
    }
    __syncthreads();  // (C)
    // main GEMM: A from aggA (LDS), B from wlF (global, coalesced 1KB/wave)
    {
      const bf16* arow = aggA + (rt * 16 + l16) * 136 + q * 8;
      const size_t lb = (size_t)lane * 8;
      const size_t kb = (size_t)(ch * 4) * 512;
      const bf16* w0f = wlF + (size_t)(2 * cw + 0) * 17408 + kb + lb;
      const bf16* w1f = wlF + (size_t)(2 * cw + 1) * 17408 + kb + lb;
      const bf16* w2f = wlF + (size_t)(2 * cw + 4) * 17408 + kb + lb;
      const bf16* w3f = wlF + (size_t)(2 * cw + 5) * 17408 + kb + lb;
      for (int kk = 0; kk < nkk; ++kk) {
        bf16x8 af = *(const bf16x8*)(arow + kk * 32);
        bf16x8 bf0 = *(const bf16x8*)(w0f + kk * 512);
        bf16x8 bf1 = *(const bf16x8*)(w1f + kk * 512);
        bf16x8 bf2 = *(const bf16x8*)(w2f + kk * 512);
        bf16x8 bf3 = *(const bf16x8*)(w3f + kk * 512);
        a00 = __builtin_amdgcn_mfma_f32_16x16x32_bf16(af, bf0, a00, 0, 0, 0);
        a01 = __builtin_amdgcn_mfma_f32_16x16x32_bf16(af, bf1, a01, 0, 0, 0);
        a10 = __builtin_amdgcn_mfma_f32_16x16x32_bf16(af, bf2, a10, 0, 0, 0);
        a11 = __builtin_amdgcn_mfma_f32_16x16x32_bf16(af, bf3, a11, 0, 0, 0);
      }
    }
  }

  __syncthreads();
  // ---- epilogue: +bl, LN(128), *gl+bel, leaky, transposed f32 store ----
  float* out_s = (float*)w_sT;  // [32][132]; w_sT dead now
  {
    int row = rt * 16 + q * 4;
    int c0 = (2 * cw + 0) * 16 + l16;
    int c1 = (2 * cw + 1) * 16 + l16;
    int c2 = 64 + c0;
    int c3 = 64 + c1;
    float bl0 = blp[c0], bl1 = blp[c1], bl2 = blp[c2], bl3 = blp[c3];
#pragma unroll
    for (int r = 0; r < 4; ++r) {
      out_s[(row + r) * 132 + c0] = a00[r] + bl0;
      out_s[(row + r) * 132 + c1] = a01[r] + bl1;
      out_s[(row + r) * 132 + c2] = a10[r] + bl2;
      out_s[(row + r) * 132 + c3] = a11[r] + bl3;
    }
  }
  __syncthreads();
  {
    int r = tid >> 3, g = tid & 7;
    const float* rowp = out_s + r * 132;
    float s1 = 0.f;
#pragma unroll
    for (int i = 0; i < 16; ++i) s1 += rowp[g + 8 * i];
    s1 += __shfl_xor(s1, 1);
    s1 += __shfl_xor(s1, 2);
    s1 += __shfl_xor(s1, 4);
    float m = s1 * (1.0f / 128.0f);
    float s2 = 0.f;
#pragma unroll
    for (int i = 0; i < 16; ++i) { float d = rowp[g + 8 * i] - m; s2 += d * d; }
    s2 += __shfl_xor(s2, 1);
    s2 += __shfl_xor(s2, 2);
    s2 += __shfl_xor(s2, 4);
    if (g == 0) {
      ln_m[r] = m;
      ln_i[r] = rsqrtf(s2 * (1.0f / 128.0f) + 1e-5f);
    }
  }
  __syncthreads();
  {
    int d = tid >> 1, sh = tid & 1;
    float gld = glp[d], beld = belp[d];
    float vals[16];
#pragma unroll
    for (int j = 0; j < 16; ++j) {
      int r = sh * 16 + j;
      float v = (out_s[r * 132 + d] - ln_m[r]) * ln_i[r] * gld + beld;
      vals[j] = v < 0.f ? 0.2f * v : v;
    }
    float* op = out + ((size_t)b * DOUT + d) * S_ + s0 + sh * 16;
#pragma unroll
    for (int i = 0; i < 4; ++i)
      *(float4*)(op + 4 * i) =
          make_float4(vals[4 * i], vals[4 * i + 1], vals[4 * i + 2], vals[4 * i + 3]);
  }
}

extern "C" void kernel_launch(void* const* d_in, const int* in_sizes, int n_in,
                              void* d_out, int out_size, void* d_ws, size_t ws_size,
                              hipStream_t stream) {
  const float* xyz  = (const float*)d_in[0];
  const float* pts  = (const float*)d_in[1];
  const float* nxyz = (const float*)d_in[2];
  const int* nnidx  = (const int*)d_in[3];
  const float* w0p  = (const float*)d_in[4];
  const float* b0p  = (const float*)d_in[5];
  const float* g0p  = (const float*)d_in[6];
  const float* be0p = (const float*)d_in[7];
  const float* w1p  = (const float*)d_in[8];
  const float* b1p  = (const float*)d_in[9];
  const float* g1p  = (const float*)d_in[10];
  const float* be1p = (const float*)d_in[11];
  const float* w2p  = (const float*)d_in[12];
  const float* b2p  = (const float*)d_in[13];
  const float* g2p  = (const float*)d_in[14];
  const float* be2p = (const float*)d_in[15];
  const float* wlp  = (const float*)d_in[16];
  const float* blp  = (const float*)d_in[17];
  const float* glp  = (const float*)d_in[18];
  const float* belp = (const float*)d_in[19];
  float* out = (float*)d_out;

  const size_t PTT_BYTES = (size_t)B_ * N_ * 64 * 2;       // 33.55 MB
  const size_t WLF_BYTES = (size_t)8 * 34 * 64 * 8 * 2;    // 0.27 MB
  bf16* ptT = (bf16*)d_ws;
  bf16* wlF = (bf16*)((char*)d_ws + PTT_BYTES);

  (void)hipGetLastError();

  if (ws_size < PTT_BYTES + WLF_BYTES) {
    k_fill<<<dim3(8), dim3(256), 0, stream>>>(out, 5000.0f);
    return;
  }

  k_transpose<<<dim3(N_ / 256, B_), dim3(256), 0, stream>>>(pts, ptT);
  hipError_t e1 = hipGetLastError();
  k_wlf<<<dim3(8 * 34), dim3(256), 0, stream>>>(wlp, wlF);
  hipError_t e2 = hipGetLastError();
  k_main<<<dim3(S_ / TS, B_), dim3(256), 0, stream>>>(
      xyz, nxyz, nnidx, ptT, wlF,
      w0p, b0p, g0p, be0p, w1p, b1p, g1p, be1p,
      w2p, b2p, g2p, be2p, blp, glp, belp, out);
  hipError_t e3 = hipGetLastError();

  if (e1 != hipSuccess)
    k_fill<<<dim3(8), dim3(256), 0, stream>>>(out, 2000.0f + (float)(int)e1);
  if (e2 != hipSuccess)
    k_fill<<<dim3(8), dim3(256), 0, stream>>>(out, 3000.0f + (float)(int)e2);
  if (e3 != hipSuccess)
    k_fill<<<dim3(8), dim3(256), 0, stream>>>(out, 4000.0f + (float)(int)e3);
}

// Round 3
// 238.907 us; speedup vs baseline: 1.1053x; 1.0058x over previous
//
#include <hip/hip_runtime.h>

#define B_ 16
#define N_ 16384
#define S_ 4096
#define K_ 16
#define TS 32
#define DOUT 128

typedef __bf16 bf16;
typedef __attribute__((ext_vector_type(8))) __bf16 bf16x8;
typedef __attribute__((ext_vector_type(4))) float f32x4;

__device__ __forceinline__ unsigned pack2(float a, float b) {
  unsigned short ua = __builtin_bit_cast(unsigned short, (bf16)a);
  unsigned short ub = __builtin_bit_cast(unsigned short, (bf16)b);
  return (unsigned)ua | ((unsigned)ub << 16);
}

template <int NCH>
__device__ __forceinline__ void ln_leaky(const float* h, const float* g, const float* e, float* o) {
  float m = 0.f;
#pragma unroll
  for (int j = 0; j < NCH; ++j) m += h[j];
  m *= (1.0f / NCH);
  float v = 0.f;
#pragma unroll
  for (int j = 0; j < NCH; ++j) { float d = h[j] - m; v += d * d; }
  v *= (1.0f / NCH);
  float inv = rsqrtf(v + 1e-5f);
#pragma unroll
  for (int j = 0; j < NCH; ++j) {
    float t = (h[j] - m) * inv * g[j] + e[j];
    o[j] = t < 0.f ? 0.2f * t : t;
  }
}

__global__ void k_fill(float* out, float v) {
  out[blockIdx.x * 256 + threadIdx.x] = v;
}

// Fused prep: blocks [0,1024) transpose points [B,64,N] f32 -> ptT [B,N,64] bf16
// with XCD-affine batch mapping; blocks [1024,1296) build wlF.
__global__ __launch_bounds__(256) void k_prep(const float* __restrict__ pts,
                                              bf16* __restrict__ pt,
                                              const float* __restrict__ wl,
                                              bf16* __restrict__ wlF) {
  int bi = blockIdx.x;
  if (bi < 1024) {
    int xcd = bi & 7;
    int li = bi >> 3;                  // 0..127
    int b = xcd * 2 + (li >> 6);       // batch: XCD x -> {2x, 2x+1}
    int n0 = (li & 63) * 256;
    int tc = threadIdx.x & 7;
    int tn = threadIdx.x >> 3;
    const float* src = pts + (size_t)b * 64 * N_ + (size_t)(tc * 8) * N_ + n0 + tn * 8;
    float4 row[8][2];
#pragma unroll
    for (int i = 0; i < 8; ++i) {
      row[i][0] = *(const float4*)(src + (size_t)i * N_);
      row[i][1] = *(const float4*)(src + (size_t)i * N_ + 4);
    }
    bf16* dst = pt + ((size_t)b * N_ + n0 + tn * 8) * 64 + tc * 8;
#pragma unroll
    for (int j = 0; j < 8; ++j) {
      float v[8];
#pragma unroll
      for (int i = 0; i < 8; ++i) {
        float4 q = row[i][j >> 2];
        v[i] = ((j & 3) == 0) ? q.x : ((j & 3) == 1) ? q.y : ((j & 3) == 2) ? q.z : q.w;
      }
      *(uint4*)(dst + (size_t)j * 64) = make_uint4(
          pack2(v[0], v[1]), pack2(v[2], v[3]), pack2(v[4], v[5]), pack2(v[6], v[7]));
    }
  } else {
    int blk = bi - 1024;               // t*34 + kkg
    int kkg = blk % 34;
    int t = blk / 34;
    int tid = threadIdx.x;
    int L = tid >> 2, jp = (tid & 3) * 2;
    int k = kkg * 32 + ((L >> 4) << 3) + jp;
    int n = t * 16 + (L & 15);
    float v0 = (k < 1072) ? wl[(size_t)k * 128 + n] : 0.f;
    float v1 = (k + 1 < 1072) ? wl[(size_t)(k + 1) * 128 + n] : 0.f;
    ((unsigned*)wlF)[(size_t)blk * 256 + tid] = pack2(v0, v1);
  }
}

__global__ __launch_bounds__(256, 4) void k_main(
    const float* __restrict__ xyz, const float* __restrict__ nxyz,
    const int* __restrict__ nnidx,
    const bf16* __restrict__ ptT, const bf16* __restrict__ wlF,
    const float* __restrict__ w0p, const float* __restrict__ b0p,
    const float* __restrict__ g0p, const float* __restrict__ be0p,
    const float* __restrict__ w1p, const float* __restrict__ b1p,
    const float* __restrict__ g1p, const float* __restrict__ be1p,
    const float* __restrict__ w2p, const float* __restrict__ b2p,
    const float* __restrict__ g2p, const float* __restrict__ be2p,
    const float* __restrict__ blp, const float* __restrict__ glp,
    const float* __restrict__ belp, float* __restrict__ out) {
  // LDS (35.4 KB total -> 4 blocks/CU).
  // feat2 and w_sT carry a 16B-block XOR swizzle on the k-half (element bit 3):
  //   feat2: k ^= 8*(s & 1);  w_sT: k ^= 8*((m >> 2) & 1).
  // RULE: the XOR is applied ONLY to the isolated k-component (0/8), never to a
  // composed address — 264/odd-row strides have bit 3 set and adds can carry.
  __shared__ __align__(16) bf16 w_sT[32 * 264];   // [s][m*16+k] (^swz), s-stride 264
  __shared__ __align__(16) bf16 feat2[32 * 144];  // [s][c*16+k] (^swz), s-stride 144
  __shared__ __align__(16) bf16 aggA[32 * 136];   // [s][c*16+m], s-stride 136
  __shared__ float nx[3][TS];
  __shared__ float ln_m[TS], ln_i[TS];

  const int tid = threadIdx.x;
  // XCD-affinity: XCD x owns batches {2x, 2x+1} (bijective remap).
  const unsigned Lwg = blockIdx.y * 128u + blockIdx.x;
  const int xcd = (int)(Lwg & 7u);
  const int li = (int)(Lwg >> 3);          // 0..255 within XCD
  const int b = xcd * 2 + (li >> 7);       // batch
  const int s0 = (li & 127) * TS;          // s-tile origin
  const size_t ibase = ((size_t)b * S_ + s0) * K_;

  if (tid < 96) {
    int c = tid >> 5, j = tid & 31;
    nx[c][j] = nxyz[((size_t)b * 3 + c) * S_ + s0 + j];
  }
  // gather-phase indices (this thread's two points), register-resident
  const int ig0 = nnidx[ibase + tid];
  const int ig1 = nnidx[ibase + tid + 256];
  // weightnet-phase indices (points 2*tid, 2*tid+1)
  const int iw0 = nnidx[ibase + 2 * tid];
  const int iw1 = nnidx[ibase + 2 * tid + 1];

  const bf16* ptB = ptT + (size_t)b * N_ * 64;
  // Issue the first two chunks' gathers NOW; WeightNet's ~1400cy of VALU
  // covers their latency.
  uint4 pfA0 = *(const uint4*)(ptB + (size_t)ig0 * 64);
  uint4 pfA1 = *(const uint4*)(ptB + (size_t)ig1 * 64);
  uint4 pfB0 = *(const uint4*)(ptB + (size_t)ig0 * 64 + 8);
  uint4 pfB1 = *(const uint4*)(ptB + (size_t)ig1 * 64 + 8);
  __syncthreads();  // nx ready

  // ---- WeightNet: points p0=2*tid (s=tid>>3, k0=2*(tid&7)) and p0+1 ----
  float xa[3], xb[3];
  const int ws = tid >> 3;        // s for weightnet outputs
  const int wk = (tid & 7) * 2;   // even k
  {
#pragma unroll
    for (int c = 0; c < 3; ++c) {
      float nv = nx[c][ws];
      xa[c] = xyz[((size_t)b * 3 + c) * N_ + iw0] - nv;
      xb[c] = xyz[((size_t)b * 3 + c) * N_ + iw1] - nv;
    }
    float ya[8], yb[8];
    {
      float h0[8], h1[8];
#pragma unroll
      for (int j = 0; j < 8; ++j) {
        h0[j] = b0p[j] + xa[0] * w0p[j] + xa[1] * w0p[8 + j] + xa[2] * w0p[16 + j];
        h1[j] = b0p[j] + xb[0] * w0p[j] + xb[1] * w0p[8 + j] + xb[2] * w0p[16 + j];
      }
      ln_leaky<8>(h0, g0p, be0p, ya);
      ln_leaky<8>(h1, g0p, be0p, yb);
    }
    {
      float h0[8], h1[8];
#pragma unroll
      for (int j = 0; j < 8; ++j) { h0[j] = b1p[j]; h1[j] = b1p[j]; }
#pragma unroll
      for (int i = 0; i < 8; ++i) {
#pragma unroll
        for (int j = 0; j < 8; ++j) {
          float w = w1p[i * 8 + j];
          h0[j] += ya[i] * w; h1[j] += yb[i] * w;
        }
      }
      ln_leaky<8>(h0, g1p, be1p, ya);
      ln_leaky<8>(h1, g1p, be1p, yb);
    }
    {
      float h0[16], h1[16];
#pragma unroll
      for (int j = 0; j < 16; ++j) { h0[j] = b2p[j]; h1[j] = b2p[j]; }
#pragma unroll
      for (int i = 0; i < 8; ++i) {
#pragma unroll
        for (int j = 0; j < 16; ++j) {
          float w = w2p[i * 16 + j];
          h0[j] += ya[i] * w; h1[j] += yb[i] * w;
        }
      }
      float z0[16], z1[16];
      ln_leaky<16>(h0, g2p, be2p, z0);
      ln_leaky<16>(h1, g2p, be2p, z1);
      // w_sT[s][m*16 + (wk ^ 8*sigma(m))]; XOR on wk ONLY (bit-3-clean).
      bf16* wpA = w_sT + ws * 264 + wk;
      bf16* wpB = w_sT + ws * 264 + (wk ^ 8);
#pragma unroll
      for (int m = 0; m < 16; ++m) {
        bf16* wp = (((m >> 2) & 1) ? wpB : wpA);
        *(unsigned*)(wp + m * 16) = pack2(z0[m], z1[m]);
      }
    }
  }

  // ---- MFMA wave geometry ----
  const int lane = tid & 63;
  const int wv = tid >> 6;
  const int rt = wv & 1;        // main-GEMM row tile
  const int cw = wv >> 1;       // main-GEMM col pair
  const int l16 = lane & 15;
  const int q = lane >> 4;
  // agg-MFMA lane roles; swizzle XOR folded into the 0/8 k-constant (no carry).
  const bool adiag = ((((lane >> 5) ^ (lane >> 3)) & 1) == 0);
  const int aoff = ((lane >> 3) & 1) * 144 + (lane & 7) * 16 +
                   (((q & 1) ^ ((lane >> 3) & 1)) << 3);
  const int boff = (lane >> 5) * 264 + l16 * 16 +
                   (((q & 1) ^ ((l16 >> 2) & 1)) << 3);
  const int soff = (lane >> 5) * 136 + (q & 1) * 64 + l16;  // + r*16
  f32x4 a00 = {0.f, 0.f, 0.f, 0.f};
  f32x4 a01 = a00, a10 = a00, a11 = a00;
  const f32x4 zc = a00;

  const int gs0 = tid >> 4, gk = tid & 15;  // gather slots: s=gs0 / gs0+16, k=gk
  bf16* f0 = feat2 + gs0 * 144 + (gk ^ ((gs0 & 1) << 3));
  bf16* f1 = f0 + 16 * 144;

  auto stage_pair = [&](const uint4& p0, const uint4& p1) {
    bf16 t0[8], t1[8];
    *(uint4*)t0 = p0;
    *(uint4*)t1 = p1;
#pragma unroll
    for (int c = 0; c < 8; ++c) {
      f0[c * 16] = t0[c];
      f1[c * 16] = t1[c];
    }
  };

  // Prologue: stage chunk 0, refill pfA with chunk 2.
  stage_pair(pfA0, pfA1);
  pfA0 = *(const uint4*)(ptB + (size_t)ig0 * 64 + 16);
  pfA1 = *(const uint4*)(ptB + (size_t)ig1 * 64 + 16);
  __syncthreads();  // w_sT + feat2(0) ready

  // Pipeline per chunk: agg(ch) | B | {stage(ch+1) || main(ch)} | A'
  for (int ch = 0; ch < 9; ++ch) {
    const int nkk = (ch < 8) ? 4 : 2;
    // agg via block-diagonal MFMA: 2 s per MFMA, 4 MFMAs per wave
#pragma unroll
    for (int pp = 0; pp < 4; ++pp) {
      int s2 = (wv * 4 + pp) * 2;
      uint4 au = *(const uint4*)(feat2 + s2 * 144 + aoff);
      if (!adiag) au = make_uint4(0u, 0u, 0u, 0u);
      bf16x8 af = __builtin_bit_cast(bf16x8, au);
      bf16x8 bw = *(const bf16x8*)(w_sT + s2 * 264 + boff);
      f32x4 d = __builtin_amdgcn_mfma_f32_16x16x32_bf16(af, bw, zc, 0, 0, 0);
      bf16* cp = aggA + s2 * 136 + soff;
#pragma unroll
      for (int r = 0; r < 4; ++r) cp[r * 16] = (bf16)d[r];
    }
    __syncthreads();  // (B) aggA ready; feat2 free for restaging
    // stage next chunk (overlaps with main GEMM below)
    if (ch < 7) {
      if (ch & 1) {
        stage_pair(pfA0, pfA1);
        if (ch <= 4) {
          pfA0 = *(const uint4*)(ptB + (size_t)ig0 * 64 + (ch + 3) * 8);
          pfA1 = *(const uint4*)(ptB + (size_t)ig1 * 64 + (ch + 3) * 8);
        }
      } else {
        stage_pair(pfB0, pfB1);
        if (ch <= 4) {
          pfB0 = *(const uint4*)(ptB + (size_t)ig0 * 64 + (ch + 3) * 8);
          pfB1 = *(const uint4*)(ptB + (size_t)ig1 * 64 + (ch + 3) * 8);
        }
      }
    } else if (ch == 7) {
      // gxn chunk (3 real + 5 zero channels), packed pairs (wk, wk+1)
      bf16* fp = feat2 + ws * 144 + (wk ^ ((ws & 1) << 3));
      *(unsigned*)(fp + 0 * 16) = pack2(xa[0], xb[0]);
      *(unsigned*)(fp + 1 * 16) = pack2(xa[1], xb[1]);
      *(unsigned*)(fp + 2 * 16) = pack2(xa[2], xb[2]);
#pragma unroll
      for (int c = 3; c < 8; ++c) *(unsigned*)(fp + c * 16) = 0u;
    }
    // main GEMM: A from aggA (LDS), B from wlF (global, coalesced 1KB/wave)
    __builtin_amdgcn_s_setprio(1);
    {
      const bf16* arow = aggA + (rt * 16 + l16) * 136 + q * 8;
      const size_t lb = (size_t)lane * 8;
      const size_t kb = (size_t)(ch * 4) * 512;
      const bf16* w0f = wlF + (size_t)(2 * cw + 0) * 17408 + kb + lb;
      const bf16* w1f = wlF + (size_t)(2 * cw + 1) * 17408 + kb + lb;
      const bf16* w2f = wlF + (size_t)(2 * cw + 4) * 17408 + kb + lb;
      const bf16* w3f = wlF + (size_t)(2 * cw + 5) * 17408 + kb + lb;
      for (int kk = 0; kk < nkk; ++kk) {
        bf16x8 af = *(const bf16x8*)(arow + kk * 32);
        bf16x8 bf0 = *(const bf16x8*)(w0f + kk * 512);
        bf16x8 bf1 = *(const bf16x8*)(w1f + kk * 512);
        bf16x8 bf2 = *(const bf16x8*)(w2f + kk * 512);
        bf16x8 bf3 = *(const bf16x8*)(w3f + kk * 512);
        a00 = __builtin_amdgcn_mfma_f32_16x16x32_bf16(af, bf0, a00, 0, 0, 0);
        a01 = __builtin_amdgcn_mfma_f32_16x16x32_bf16(af, bf1, a01, 0, 0, 0);
        a10 = __builtin_amdgcn_mfma_f32_16x16x32_bf16(af, bf2, a10, 0, 0, 0);
        a11 = __builtin_amdgcn_mfma_f32_16x16x32_bf16(af, bf3, a11, 0, 0, 0);
      }
    }
    __builtin_amdgcn_s_setprio(0);
    __syncthreads();  // (A') feat2(ch+1) ready; aggA free for next agg
  }

  // ---- epilogue: +bl, LN(128), *gl+bel, leaky, transposed f32 store ----
  float* out_s = (float*)w_sT;  // [32][132]; w_sT dead now (last read pre-B(8))
  {
    int row = rt * 16 + q * 4;
    int c0 = (2 * cw + 0) * 16 + l16;
    int c1 = (2 * cw + 1) * 16 + l16;
    int c2 = 64 + c0;
    int c3 = 64 + c1;
    float bl0 = blp[c0], bl1 = blp[c1], bl2 = blp[c2], bl3 = blp[c3];
#pragma unroll
    for (int r = 0; r < 4; ++r) {
      out_s[(row + r) * 132 + c0] = a00[r] + bl0;
      out_s[(row + r) * 132 + c1] = a01[r] + bl1;
      out_s[(row + r) * 132 + c2] = a10[r] + bl2;
      out_s[(row + r) * 132 + c3] = a11[r] + bl3;
    }
  }
  __syncthreads();
  {
    int r = tid >> 3, g = tid & 7;
    const float* rowp = out_s + r * 132;
    float s1 = 0.f;
#pragma unroll
    for (int i = 0; i < 16; ++i) s1 += rowp[g + 8 * i];
    s1 += __shfl_xor(s1, 1);
    s1 += __shfl_xor(s1, 2);
    s1 += __shfl_xor(s1, 4);
    float m = s1 * (1.0f / 128.0f);
    float s2 = 0.f;
#pragma unroll
    for (int i = 0; i < 16; ++i) { float d = rowp[g + 8 * i] - m; s2 += d * d; }
    s2 += __shfl_xor(s2, 1);
    s2 += __shfl_xor(s2, 2);
    s2 += __shfl_xor(s2, 4);
    if (g == 0) {
      ln_m[r] = m;
      ln_i[r] = rsqrtf(s2 * (1.0f / 128.0f) + 1e-5f);
    }
  }
  __syncthreads();
  {
    int d = tid >> 1, sh = tid & 1;
    float gld = glp[d], beld = belp[d];
    float vals[16];
#pragma unroll
    for (int j = 0; j < 16; ++j) {
      int r = sh * 16 + j;
      float v = (out_s[r * 132 + d] - ln_m[r]) * ln_i[r] * gld + beld;
      vals[j] = v < 0.f ? 0.2f * v : v;
    }
    float* op = out + ((size_t)b * DOUT + d) * S_ + s0 + sh * 16;
#pragma unroll
    for (int i = 0; i < 4; ++i)
      *(float4*)(op + 4 * i) =
          make_float4(vals[4 * i], vals[4 * i + 1], vals[4 * i + 2], vals[4 * i + 3]);
  }
}

extern "C" void kernel_launch(void* const* d_in, const int* in_sizes, int n_in,
                              void* d_out, int out_size, void* d_ws, size_t ws_size,
                              hipStream_t stream) {
  const float* xyz  = (const float*)d_in[0];
  const float* pts  = (const float*)d_in[1];
  const float* nxyz = (const float*)d_in[2];
  const int* nnidx  = (const int*)d_in[3];
  const float* w0p  = (const float*)d_in[4];
  const float* b0p  = (const float*)d_in[5];
  const float* g0p  = (const float*)d_in[6];
  const float* be0p = (const float*)d_in[7];
  const float* w1p  = (const float*)d_in[8];
  const float* b1p  = (const float*)d_in[9];
  const float* g1p  = (const float*)d_in[10];
  const float* be1p = (const float*)d_in[11];
  const float* w2p  = (const float*)d_in[12];
  const float* b2p  = (const float*)d_in[13];
  const float* g2p  = (const float*)d_in[14];
  const float* be2p = (const float*)d_in[15];
  const float* wlp  = (const float*)d_in[16];
  const float* blp  = (const float*)d_in[17];
  const float* glp  = (const float*)d_in[18];
  const float* belp = (const float*)d_in[19];
  float* out = (float*)d_out;

  const size_t PTT_BYTES = (size_t)B_ * N_ * 64 * 2;       // 33.55 MB
  const size_t WLF_BYTES = (size_t)8 * 34 * 64 * 8 * 2;    // 0.27 MB
  bf16* ptT = (bf16*)d_ws;
  bf16* wlF = (bf16*)((char*)d_ws + PTT_BYTES);

  (void)hipGetLastError();

  if (ws_size < PTT_BYTES + WLF_BYTES) {
    k_fill<<<dim3(8), dim3(256), 0, stream>>>(out, 5000.0f);
    return;
  }

  k_prep<<<dim3(1024 + 8 * 34), dim3(256), 0, stream>>>(pts, ptT, wlp, wlF);
  hipError_t e1 = hipGetLastError();
  k_main<<<dim3(S_ / TS, B_), dim3(256), 0, stream>>>(
      xyz, nxyz, nnidx, ptT, wlF,
      w0p, b0p, g0p, be0p, w1p, b1p, g1p, be1p,
      w2p, b2p, g2p, be2p, blp, glp, belp, out);
  hipError_t e3 = hipGetLastError();

  if (e1 != hipSuccess)
    k_fill<<<dim3(8), dim3(256), 0, stream>>>(out, 2000.0f + (float)(int)e1);
  if (e3 != hipSuccess)
    k_fill<<<dim3(8), dim3(256), 0, stream>>>(out, 4000.0f + (float)(int)e3);
}

// Round 4
// 232.909 us; speedup vs baseline: 1.1338x; 1.0258x over previous
//
#include <hip/hip_runtime.h>

#define B_ 16
#define N_ 16384
#define S_ 4096
#define K_ 16
#define TS 32
#define DOUT 128

typedef __bf16 bf16;
typedef __attribute__((ext_vector_type(8))) __bf16 bf16x8;
typedef __attribute__((ext_vector_type(4))) float f32x4;

__device__ __forceinline__ unsigned pack2(float a, float b) {
  unsigned short ua = __builtin_bit_cast(unsigned short, (bf16)a);
  unsigned short ub = __builtin_bit_cast(unsigned short, (bf16)b);
  return (unsigned)ua | ((unsigned)ub << 16);
}

template <int NCH>
__device__ __forceinline__ void ln_leaky(const float* h, const float* g, const float* e, float* o) {
  float m = 0.f;
#pragma unroll
  for (int j = 0; j < NCH; ++j) m += h[j];
  m *= (1.0f / NCH);
  float v = 0.f;
#pragma unroll
  for (int j = 0; j < NCH; ++j) { float d = h[j] - m; v += d * d; }
  v *= (1.0f / NCH);
  float inv = rsqrtf(v + 1e-5f);
#pragma unroll
  for (int j = 0; j < NCH; ++j) {
    float t = (h[j] - m) * inv * g[j] + e[j];
    o[j] = t < 0.f ? 0.2f * t : t;
  }
}

__global__ void k_fill(float* out, float v) {
  out[blockIdx.x * 256 + threadIdx.x] = v;
}

// Fused prep: blocks [0,1024) transpose points [B,64,N] f32 -> ptT [B,N,64] bf16
// with XCD-affine batch mapping; blocks [1024,1296) build wlF.
__global__ __launch_bounds__(256) void k_prep(const float* __restrict__ pts,
                                              bf16* __restrict__ pt,
                                              const float* __restrict__ wl,
                                              bf16* __restrict__ wlF) {
  int bi = blockIdx.x;
  if (bi < 1024) {
    int xcd = bi & 7;
    int li = bi >> 3;                  // 0..127
    int b = xcd * 2 + (li >> 6);       // batch: XCD x -> {2x, 2x+1}
    int n0 = (li & 63) * 256;
    int tc = threadIdx.x & 7;
    int tn = threadIdx.x >> 3;
    const float* src = pts + (size_t)b * 64 * N_ + (size_t)(tc * 8) * N_ + n0 + tn * 8;
    float4 row[8][2];
#pragma unroll
    for (int i = 0; i < 8; ++i) {
      row[i][0] = *(const float4*)(src + (size_t)i * N_);
      row[i][1] = *(const float4*)(src + (size_t)i * N_ + 4);
    }
    bf16* dst = pt + ((size_t)b * N_ + n0 + tn * 8) * 64 + tc * 8;
#pragma unroll
    for (int j = 0; j < 8; ++j) {
      float v[8];
#pragma unroll
      for (int i = 0; i < 8; ++i) {
        float4 q = row[i][j >> 2];
        v[i] = ((j & 3) == 0) ? q.x : ((j & 3) == 1) ? q.y : ((j & 3) == 2) ? q.z : q.w;
      }
      *(uint4*)(dst + (size_t)j * 64) = make_uint4(
          pack2(v[0], v[1]), pack2(v[2], v[3]), pack2(v[4], v[5]), pack2(v[6], v[7]));
    }
  } else {
    int blk = bi - 1024;               // t*34 + kkg
    int kkg = blk % 34;
    int t = blk / 34;
    int tid = threadIdx.x;
    int L = tid >> 2, jp = (tid & 3) * 2;
    int k = kkg * 32 + ((L >> 4) << 3) + jp;
    int n = t * 16 + (L & 15);
    float v0 = (k < 1072) ? wl[(size_t)k * 128 + n] : 0.f;
    float v1 = (k + 1 < 1072) ? wl[(size_t)(k + 1) * 128 + n] : 0.f;
    ((unsigned*)wlF)[(size_t)blk * 256 + tid] = pack2(v0, v1);
  }
}

__global__ __launch_bounds__(256, 4) void k_main(
    const float* __restrict__ xyz, const float* __restrict__ nxyz,
    const int* __restrict__ nnidx,
    const bf16* __restrict__ ptT, const bf16* __restrict__ wlF,
    const float* __restrict__ w0p, const float* __restrict__ b0p,
    const float* __restrict__ g0p, const float* __restrict__ be0p,
    const float* __restrict__ w1p, const float* __restrict__ b1p,
    const float* __restrict__ g1p, const float* __restrict__ be1p,
    const float* __restrict__ w2p, const float* __restrict__ b2p,
    const float* __restrict__ g2p, const float* __restrict__ be2p,
    const float* __restrict__ blp, const float* __restrict__ glp,
    const float* __restrict__ belp, float* __restrict__ out) {
  // LDS (35.4 KB total -> 4 blocks/CU):
  __shared__ __align__(16) bf16 w_sT[32 * 264];   // [s][m*16+k], s-stride 264 (pad 8)
  __shared__ __align__(16) bf16 feat2[32 * 144];  // [s][c*16+k], s-stride 144 (pad 16)
  __shared__ __align__(16) bf16 aggA[32 * 136];   // [s][c*16+m], s-stride 136 (pad 8)
  __shared__ float nx[3][TS];
  __shared__ float ln_m[TS], ln_i[TS];

  const int tid = threadIdx.x;
  // XCD-affinity: XCD x owns batches {2x, 2x+1} (bijective remap).
  const unsigned Lwg = blockIdx.y * 128u + blockIdx.x;
  const int xcd = (int)(Lwg & 7u);
  const int li = (int)(Lwg >> 3);          // 0..255 within XCD
  const int b = xcd * 2 + (li >> 7);       // batch
  const int s0 = (li & 127) * TS;          // s-tile origin
  const size_t ibase = ((size_t)b * S_ + s0) * K_;

  if (tid < 96) {
    int c = tid >> 5, j = tid & 31;
    nx[c][j] = nxyz[((size_t)b * 3 + c) * S_ + s0 + j];
  }
  // gather-phase indices (this thread's two points), register-resident
  const int ig0 = nnidx[ibase + tid];
  const int ig1 = nnidx[ibase + tid + 256];
  // weightnet-phase indices (points 2*tid, 2*tid+1)
  const int iw0 = nnidx[ibase + 2 * tid];
  const int iw1 = nnidx[ibase + 2 * tid + 1];
  __syncthreads();

  // ---- WeightNet: points p0=2*tid (s=tid>>3, k0=2*(tid&7)) and p0+1 ----
  float xa[3], xb[3];
  const int ws = tid >> 3;        // s for weightnet outputs
  const int wk = (tid & 7) * 2;   // even k
  {
#pragma unroll
    for (int c = 0; c < 3; ++c) {
      float nv = nx[c][ws];
      xa[c] = xyz[((size_t)b * 3 + c) * N_ + iw0] - nv;
      xb[c] = xyz[((size_t)b * 3 + c) * N_ + iw1] - nv;
    }
    float ya[8], yb[8];
    {
      float h0[8], h1[8];
#pragma unroll
      for (int j = 0; j < 8; ++j) {
        h0[j] = b0p[j] + xa[0] * w0p[j] + xa[1] * w0p[8 + j] + xa[2] * w0p[16 + j];
        h1[j] = b0p[j] + xb[0] * w0p[j] + xb[1] * w0p[8 + j] + xb[2] * w0p[16 + j];
      }
      ln_leaky<8>(h0, g0p, be0p, ya);
      ln_leaky<8>(h1, g0p, be0p, yb);
    }
    {
      float h0[8], h1[8];
#pragma unroll
      for (int j = 0; j < 8; ++j) { h0[j] = b1p[j]; h1[j] = b1p[j]; }
#pragma unroll
      for (int i = 0; i < 8; ++i) {
#pragma unroll
        for (int j = 0; j < 8; ++j) {
          float w = w1p[i * 8 + j];
          h0[j] += ya[i] * w; h1[j] += yb[i] * w;
        }
      }
      ln_leaky<8>(h0, g1p, be1p, ya);
      ln_leaky<8>(h1, g1p, be1p, yb);
    }
    {
      float h0[16], h1[16];
#pragma unroll
      for (int j = 0; j < 16; ++j) { h0[j] = b2p[j]; h1[j] = b2p[j]; }
#pragma unroll
      for (int i = 0; i < 8; ++i) {
#pragma unroll
        for (int j = 0; j < 16; ++j) {
          float w = w2p[i * 16 + j];
          h0[j] += ya[i] * w; h1[j] += yb[i] * w;
        }
      }
      float z0[16], z1[16];
      ln_leaky<16>(h0, g2p, be2p, z0);
      ln_leaky<16>(h1, g2p, be2p, z1);
      // w_sT[s][m*16+k]: pack both k's (wk, wk+1) into one b32 per m
      bf16* wp = w_sT + ws * 264 + wk;
#pragma unroll
      for (int m = 0; m < 16; ++m)
        *(unsigned*)(wp + m * 16) = pack2(z0[m], z1[m]);
    }
  }

  // ---- MFMA wave geometry ----
  const int lane = tid & 63;
  const int wv = tid >> 6;
  const int l16 = lane & 15;
  const int q = lane >> 4;
  // Main GEMM: each wave owns 2 row-tiles x 2 col-tiles (tiles wv and wv+4).
  // This halves wlF B-fragment loads per wave (8 vs 16 b128/chunk) and total
  // wlF L2 traffic (1.2 GB -> 0.6 GB) vs the 1rt x 4ct mapping.
  // agg-MFMA lane roles
  const bool adiag = ((((lane >> 5) ^ (lane >> 3)) & 1) == 0);
  const int aoff = ((lane >> 3) & 1) * 144 + (lane & 7) * 16 + (q & 1) * 8;
  const int boff = (lane >> 5) * 264 + l16 * 16 + (q & 1) * 8;
  const int soff = (lane >> 5) * 136 + (q & 1) * 64 + l16;  // + r*16
  f32x4 a00 = {0.f, 0.f, 0.f, 0.f};
  f32x4 a01 = a00, a10 = a00, a11 = a00;
  const f32x4 zc = a00;

  const bf16* ptB = ptT + (size_t)b * N_ * 64;
  const int gs0 = tid >> 4, gk = tid & 15;  // gather slots: s=gs0 / gs0+16, k=gk

  uint4 pf0, pf1;
  pf0 = *(const uint4*)(ptB + (size_t)ig0 * 64);
  pf1 = *(const uint4*)(ptB + (size_t)ig1 * 64);

  for (int ch = 0; ch < 9; ++ch) {
    const int nkk = (ch < 8) ? 4 : 2;
    __syncthreads();  // (A) prev agg done with feat2/w_sT reads; prev main done with aggA
    // stage feat2[s][c*16+k] for this chunk
    if (ch < 8) {
      bf16 t0[8], t1[8];
      *(uint4*)t0 = pf0;
      *(uint4*)t1 = pf1;
      bf16* f0 = feat2 + gs0 * 144 + gk;
      bf16* f1 = feat2 + (gs0 + 16) * 144 + gk;
#pragma unroll
      for (int c = 0; c < 8; ++c) {
        f0[c * 16] = t0[c];
        f1[c * 16] = t1[c];
      }
    } else {
      // gxn channels (3 real + 5 zero), packed pairs (wk, wk+1)
      bf16* fp = feat2 + ws * 144 + wk;
      *(unsigned*)(fp + 0 * 16) = pack2(xa[0], xb[0]);
      *(unsigned*)(fp + 1 * 16) = pack2(xa[1], xb[1]);
      *(unsigned*)(fp + 2 * 16) = pack2(xa[2], xb[2]);
#pragma unroll
      for (int c = 3; c < 8; ++c) *(unsigned*)(fp + c * 16) = 0u;
    }
    __syncthreads();  // (B)
    if (ch < 8) {  // prefetch next chunk's gather
      int nc = ch + 1;
      if (nc < 8) {
        pf0 = *(const uint4*)(ptB + (size_t)ig0 * 64 + nc * 8);
        pf1 = *(const uint4*)(ptB + (size_t)ig1 * 64 + nc * 8);
      }
    }
    // agg via block-diagonal MFMA: 2 s per MFMA, 4 MFMAs per wave
#pragma unroll
    for (int pp = 0; pp < 4; ++pp) {
      int s2 = (wv * 4 + pp) * 2;
      uint4 au = *(const uint4*)(feat2 + s2 * 144 + aoff);
      if (!adiag) au = make_uint4(0u, 0u, 0u, 0u);
      bf16x8 af = __builtin_bit_cast(bf16x8, au);
      bf16x8 bw = *(const bf16x8*)(w_sT + s2 * 264 + boff);
      f32x4 d = __builtin_amdgcn_mfma_f32_16x16x32_bf16(af, bw, zc, 0, 0, 0);
      bf16* cp = aggA + s2 * 136 + soff;
#pragma unroll
      for (int r = 0; r < 4; ++r) cp[r * 16] = (bf16)d[r];
    }
    __syncthreads();  // (C)
    // main GEMM: A from aggA (LDS), B from wlF (global, coalesced 1KB/wave).
    // Wave wv: rows 0..31 (both row-tiles), col tiles {wv, wv+4}.
    {
      const bf16* arow0 = aggA + l16 * 136 + q * 8;
      const bf16* arow1 = aggA + (16 + l16) * 136 + q * 8;
      const size_t lb = (size_t)lane * 8;
      const size_t kb = (size_t)(ch * 4) * 512;
      const bf16* w0f = wlF + (size_t)wv * 17408 + kb + lb;
      const bf16* w1f = wlF + (size_t)(wv + 4) * 17408 + kb + lb;
      for (int kk = 0; kk < nkk; ++kk) {
        bf16x8 af0 = *(const bf16x8*)(arow0 + kk * 32);
        bf16x8 af1 = *(const bf16x8*)(arow1 + kk * 32);
        bf16x8 bf0 = *(const bf16x8*)(w0f + kk * 512);
        bf16x8 bf1 = *(const bf16x8*)(w1f + kk * 512);
        a00 = __builtin_amdgcn_mfma_f32_16x16x32_bf16(af0, bf0, a00, 0, 0, 0);
        a01 = __builtin_amdgcn_mfma_f32_16x16x32_bf16(af0, bf1, a01, 0, 0, 0);
        a10 = __builtin_amdgcn_mfma_f32_16x16x32_bf16(af1, bf0, a10, 0, 0, 0);
        a11 = __builtin_amdgcn_mfma_f32_16x16x32_bf16(af1, bf1, a11, 0, 0, 0);
      }
    }
  }

  __syncthreads();
  // ---- epilogue: +bl, LN(128), *gl+bel, leaky, transposed f32 store ----
  float* out_s = (float*)w_sT;  // [32][132]; w_sT dead now
  {
    // a00: rows q*4+r,   col wv*16+l16;  a01: rows q*4+r,   col 64+wv*16+l16
    // a10: rows 16+q*4+r, same cols.
    int row0 = q * 4;
    int row1 = 16 + q * 4;
    int c0 = wv * 16 + l16;
    int c1 = 64 + c0;
    float bl0 = blp[c0], bl1 = blp[c1];
#pragma unroll
    for (int r = 0; r < 4; ++r) {
      out_s[(row0 + r) * 132 + c0] = a00[r] + bl0;
      out_s[(row0 + r) * 132 + c1] = a01[r] + bl1;
      out_s[(row1 + r) * 132 + c0] = a10[r] + bl0;
      out_s[(row1 + r) * 132 + c1] = a11[r] + bl1;
    }
  }
  __syncthreads();
  {
    int r = tid >> 3, g = tid & 7;
    const float* rowp = out_s + r * 132;
    float s1 = 0.f;
#pragma unroll
    for (int i = 0; i < 16; ++i) s1 += rowp[g + 8 * i];
    s1 += __shfl_xor(s1, 1);
    s1 += __shfl_xor(s1, 2);
    s1 += __shfl_xor(s1, 4);
    float m = s1 * (1.0f / 128.0f);
    float s2 = 0.f;
#pragma unroll
    for (int i = 0; i < 16; ++i) { float d = rowp[g + 8 * i] - m; s2 += d * d; }
    s2 += __shfl_xor(s2, 1);
    s2 += __shfl_xor(s2, 2);
    s2 += __shfl_xor(s2, 4);
    if (g == 0) {
      ln_m[r] = m;
      ln_i[r] = rsqrtf(s2 * (1.0f / 128.0f) + 1e-5f);
    }
  }
  __syncthreads();
  {
    int d = tid >> 1, sh = tid & 1;
    float gld = glp[d], beld = belp[d];
    float vals[16];
#pragma unroll
    for (int j = 0; j < 16; ++j) {
      int r = sh * 16 + j;
      float v = (out_s[r * 132 + d] - ln_m[r]) * ln_i[r] * gld + beld;
      vals[j] = v < 0.f ? 0.2f * v : v;
    }
    float* op = out + ((size_t)b * DOUT + d) * S_ + s0 + sh * 16;
#pragma unroll
    for (int i = 0; i < 4; ++i)
      *(float4*)(op + 4 * i) =
          make_float4(vals[4 * i], vals[4 * i + 1], vals[4 * i + 2], vals[4 * i + 3]);
  }
}

extern "C" void kernel_launch(void* const* d_in, const int* in_sizes, int n_in,
                              void* d_out, int out_size, void* d_ws, size_t ws_size,
                              hipStream_t stream) {
  const float* xyz  = (const float*)d_in[0];
  const float* pts  = (const float*)d_in[1];
  const float* nxyz = (const float*)d_in[2];
  const int* nnidx  = (const int*)d_in[3];
  const float* w0p  = (const float*)d_in[4];
  const float* b0p  = (const float*)d_in[5];
  const float* g0p  = (const float*)d_in[6];
  const float* be0p = (const float*)d_in[7];
  const float* w1p  = (const float*)d_in[8];
  const float* b1p  = (const float*)d_in[9];
  const float* g1p  = (const float*)d_in[10];
  const float* be1p = (const float*)d_in[11];
  const float* w2p  = (const float*)d_in[12];
  const float* b2p  = (const float*)d_in[13];
  const float* g2p  = (const float*)d_in[14];
  const float* be2p = (const float*)d_in[15];
  const float* wlp  = (const float*)d_in[16];
  const float* blp  = (const float*)d_in[17];
  const float* glp  = (const float*)d_in[18];
  const float* belp = (const float*)d_in[19];
  float* out = (float*)d_out;

  const size_t PTT_BYTES = (size_t)B_ * N_ * 64 * 2;       // 33.55 MB
  const size_t WLF_BYTES = (size_t)8 * 34 * 64 * 8 * 2;    // 0.27 MB
  bf16* ptT = (bf16*)d_ws;
  bf16* wlF = (bf16*)((char*)d_ws + PTT_BYTES);

  (void)hipGetLastError();

  if (ws_size < PTT_BYTES + WLF_BYTES) {
    k_fill<<<dim3(8), dim3(256), 0, stream>>>(out, 5000.0f);
    return;
  }

  k_prep<<<dim3(1024 + 8 * 34), dim3(256), 0, stream>>>(pts, ptT, wlp, wlF);
  hipError_t e1 = hipGetLastError();
  k_main<<<dim3(S_ / TS, B_), dim3(256), 0, stream>>>(
      xyz, nxyz, nnidx, ptT, wlF,
      w0p, b0p, g0p, be0p, w1p, b1p, g1p, be1p,
      w2p, b2p, g2p, be2p, blp, glp, belp, out);
  hipError_t e3 = hipGetLastError();

  if (e1 != hipSuccess)
    k_fill<<<dim3(8), dim3(256), 0, stream>>>(out, 2000.0f + (float)(int)e1);
  if (e3 != hipSuccess)
    k_fill<<<dim3(8), dim3(256), 0, stream>>>(out, 4000.0f + (float)(int)e3);
}

// Round 5
// 229.017 us; speedup vs baseline: 1.1531x; 1.0170x over previous
//
#include <hip/hip_runtime.h>

#define B_ 16
#define N_ 16384
#define S_ 4096
#define K_ 16
#define TS 32
#define DOUT 128

typedef __bf16 bf16;
typedef __attribute__((ext_vector_type(8))) __bf16 bf16x8;
typedef __attribute__((ext_vector_type(4))) float f32x4;

__device__ __forceinline__ unsigned pack2(float a, float b) {
  unsigned short ua = __builtin_bit_cast(unsigned short, (bf16)a);
  unsigned short ub = __builtin_bit_cast(unsigned short, (bf16)b);
  return (unsigned)ua | ((unsigned)ub << 16);
}

template <int NCH>
__device__ __forceinline__ void ln_leaky(const float* h, const float* g, const float* e, float* o) {
  float m = 0.f;
#pragma unroll
  for (int j = 0; j < NCH; ++j) m += h[j];
  m *= (1.0f / NCH);
  float v = 0.f;
#pragma unroll
  for (int j = 0; j < NCH; ++j) { float d = h[j] - m; v += d * d; }
  v *= (1.0f / NCH);
  float inv = rsqrtf(v + 1e-5f);
#pragma unroll
  for (int j = 0; j < NCH; ++j) {
    float t = (h[j] - m) * inv * g[j] + e[j];
    o[j] = t < 0.f ? 0.2f * t : t;
  }
}

__global__ void k_fill(float* out, float v) {
  out[blockIdx.x * 256 + threadIdx.x] = v;
}

// Fused prep: blocks [0,1024) transpose points [B,64,N] f32 -> ptT [B,N,64] bf16
// with XCD-affine batch mapping; blocks [1024,1296) build wlF.
__global__ __launch_bounds__(256) void k_prep(const float* __restrict__ pts,
                                              bf16* __restrict__ pt,
                                              const float* __restrict__ wl,
                                              bf16* __restrict__ wlF) {
  int bi = blockIdx.x;
  if (bi < 1024) {
    int xcd = bi & 7;
    int li = bi >> 3;                  // 0..127
    int b = xcd * 2 + (li >> 6);       // batch: XCD x -> {2x, 2x+1}
    int n0 = (li & 63) * 256;
    int tc = threadIdx.x & 7;
    int tn = threadIdx.x >> 3;
    const float* src = pts + (size_t)b * 64 * N_ + (size_t)(tc * 8) * N_ + n0 + tn * 8;
    float4 row[8][2];
#pragma unroll
    for (int i = 0; i < 8; ++i) {
      row[i][0] = *(const float4*)(src + (size_t)i * N_);
      row[i][1] = *(const float4*)(src + (size_t)i * N_ + 4);
    }
    bf16* dst = pt + ((size_t)b * N_ + n0 + tn * 8) * 64 + tc * 8;
#pragma unroll
    for (int j = 0; j < 8; ++j) {
      float v[8];
#pragma unroll
      for (int i = 0; i < 8; ++i) {
        float4 q = row[i][j >> 2];
        v[i] = ((j & 3) == 0) ? q.x : ((j & 3) == 1) ? q.y : ((j & 3) == 2) ? q.z : q.w;
      }
      *(uint4*)(dst + (size_t)j * 64) = make_uint4(
          pack2(v[0], v[1]), pack2(v[2], v[3]), pack2(v[4], v[5]), pack2(v[6], v[7]));
    }
  } else {
    int blk = bi - 1024;               // t*34 + kkg
    int kkg = blk % 34;
    int t = blk / 34;
    int tid = threadIdx.x;
    int L = tid >> 2, jp = (tid & 3) * 2;
    int k = kkg * 32 + ((L >> 4) << 3) + jp;
    int n = t * 16 + (L & 15);
    float v0 = (k < 1072) ? wl[(size_t)k * 128 + n] : 0.f;
    float v1 = (k + 1 < 1072) ? wl[(size_t)(k + 1) * 128 + n] : 0.f;
    ((unsigned*)wlF)[(size_t)blk * 256 + tid] = pack2(v0, v1);
  }
}

__global__ __launch_bounds__(256, 4) void k_main(
    const float* __restrict__ xyz, const float* __restrict__ nxyz,
    const int* __restrict__ nnidx,
    const bf16* __restrict__ ptT, const bf16* __restrict__ wlF,
    const float* __restrict__ w0p, const float* __restrict__ b0p,
    const float* __restrict__ g0p, const float* __restrict__ be0p,
    const float* __restrict__ w1p, const float* __restrict__ b1p,
    const float* __restrict__ g1p, const float* __restrict__ be1p,
    const float* __restrict__ w2p, const float* __restrict__ b2p,
    const float* __restrict__ g2p, const float* __restrict__ be2p,
    const float* __restrict__ blp, const float* __restrict__ glp,
    const float* __restrict__ belp, float* __restrict__ out) {
  // LDS (35.4 KB total -> 4 blocks/CU):
  __shared__ __align__(16) bf16 w_sT[32 * 264];   // [s][m*16+k], s-stride 264 (pad 8)
  __shared__ __align__(16) bf16 feat2[32 * 144];  // [s][c*16+k], s-stride 144 (pad 16)
  __shared__ __align__(16) bf16 aggA[32 * 136];   // [s][c*16+m], s-stride 136 (pad 8)
  __shared__ float nx[3][TS];
  __shared__ float ln_m[TS], ln_i[TS];

  const int tid = threadIdx.x;
  // XCD-affinity: XCD x owns batches {2x, 2x+1} (bijective remap).
  const unsigned Lwg = blockIdx.y * 128u + blockIdx.x;
  const int xcd = (int)(Lwg & 7u);
  const int li = (int)(Lwg >> 3);          // 0..255 within XCD
  const int b = xcd * 2 + (li >> 7);       // batch
  const int s0 = (li & 127) * TS;          // s-tile origin
  const size_t ibase = ((size_t)b * S_ + s0) * K_;

  if (tid < 96) {
    int c = tid >> 5, j = tid & 31;
    nx[c][j] = nxyz[((size_t)b * 3 + c) * S_ + s0 + j];
  }
  // gather-phase indices (this thread's two points), register-resident
  const int ig0 = nnidx[ibase + tid];
  const int ig1 = nnidx[ibase + tid + 256];
  // weightnet-phase indices (points 2*tid, 2*tid+1)
  const int iw0 = nnidx[ibase + 2 * tid];
  const int iw1 = nnidx[ibase + 2 * tid + 1];
  __syncthreads();

  // ---- WeightNet: points p0=2*tid (s=tid>>3, k0=2*(tid&7)) and p0+1 ----
  float xa[3], xb[3];
  const int ws = tid >> 3;        // s for weightnet outputs
  const int wk = (tid & 7) * 2;   // even k
  {
#pragma unroll
    for (int c = 0; c < 3; ++c) {
      float nv = nx[c][ws];
      xa[c] = xyz[((size_t)b * 3 + c) * N_ + iw0] - nv;
      xb[c] = xyz[((size_t)b * 3 + c) * N_ + iw1] - nv;
    }
    float ya[8], yb[8];
    {
      float h0[8], h1[8];
#pragma unroll
      for (int j = 0; j < 8; ++j) {
        h0[j] = b0p[j] + xa[0] * w0p[j] + xa[1] * w0p[8 + j] + xa[2] * w0p[16 + j];
        h1[j] = b0p[j] + xb[0] * w0p[j] + xb[1] * w0p[8 + j] + xb[2] * w0p[16 + j];
      }
      ln_leaky<8>(h0, g0p, be0p, ya);
      ln_leaky<8>(h1, g0p, be0p, yb);
    }
    {
      float h0[8], h1[8];
#pragma unroll
      for (int j = 0; j < 8; ++j) { h0[j] = b1p[j]; h1[j] = b1p[j]; }
#pragma unroll
      for (int i = 0; i < 8; ++i) {
#pragma unroll
        for (int j = 0; j < 8; ++j) {
          float w = w1p[i * 8 + j];
          h0[j] += ya[i] * w; h1[j] += yb[i] * w;
        }
      }
      ln_leaky<8>(h0, g1p, be1p, ya);
      ln_leaky<8>(h1, g1p, be1p, yb);
    }
    {
      float h0[16], h1[16];
#pragma unroll
      for (int j = 0; j < 16; ++j) { h0[j] = b2p[j]; h1[j] = b2p[j]; }
#pragma unroll
      for (int i = 0; i < 8; ++i) {
#pragma unroll
        for (int j = 0; j < 16; ++j) {
          float w = w2p[i * 16 + j];
          h0[j] += ya[i] * w; h1[j] += yb[i] * w;
        }
      }
      float z0[16], z1[16];
      ln_leaky<16>(h0, g2p, be2p, z0);
      ln_leaky<16>(h1, g2p, be2p, z1);
      // w_sT[s][m*16+k]: pack both k's (wk, wk+1) into one b32 per m
      bf16* wp = w_sT + ws * 264 + wk;
#pragma unroll
      for (int m = 0; m < 16; ++m)
        *(unsigned*)(wp + m * 16) = pack2(z0[m], z1[m]);
    }
  }

  // ---- MFMA wave geometry ----
  const int lane = tid & 63;
  const int wv = tid >> 6;
  const int l16 = lane & 15;
  const int q = lane >> 4;
  // Main GEMM: each wave owns 2 row-tiles x 2 col-tiles (tiles wv and wv+4).
  // This halves wlF B-fragment loads per wave (8 vs 16 b128/chunk) and total
  // wlF L2 traffic (1.2 GB -> 0.6 GB) vs the 1rt x 4ct mapping.
  // agg-MFMA lane roles
  const bool adiag = ((((lane >> 5) ^ (lane >> 3)) & 1) == 0);
  const int aoff = ((lane >> 3) & 1) * 144 + (lane & 7) * 16 + (q & 1) * 8;
  const int boff = (lane >> 5) * 264 + l16 * 16 + (q & 1) * 8;
  const int soff = (lane >> 5) * 136 + (q & 1) * 64 + l16;  // + r*16
  f32x4 a00 = {0.f, 0.f, 0.f, 0.f};
  f32x4 a01 = a00, a10 = a00, a11 = a00;
  const f32x4 zc = a00;

  const bf16* ptB = ptT + (size_t)b * N_ * 64;
  const int gs0 = tid >> 4, gk = tid & 15;  // gather slots: s=gs0 / gs0+16, k=gk

  uint4 pf0, pf1;
  pf0 = *(const uint4*)(ptB + (size_t)ig0 * 64);
  pf1 = *(const uint4*)(ptB + (size_t)ig1 * 64);

  for (int ch = 0; ch < 9; ++ch) {
    const int nkk = (ch < 8) ? 4 : 2;
    __syncthreads();  // (A) prev agg done with feat2/w_sT reads; prev main done with aggA
    // stage feat2[s][c*16+k] for this chunk
    if (ch < 8) {
      bf16 t0[8], t1[8];
      *(uint4*)t0 = pf0;
      *(uint4*)t1 = pf1;
      bf16* f0 = feat2 + gs0 * 144 + gk;
      bf16* f1 = feat2 + (gs0 + 16) * 144 + gk;
#pragma unroll
      for (int c = 0; c < 8; ++c) {
        f0[c * 16] = t0[c];
        f1[c * 16] = t1[c];
      }
    } else {
      // gxn channels (3 real + 5 zero), packed pairs (wk, wk+1)
      bf16* fp = feat2 + ws * 144 + wk;
      *(unsigned*)(fp + 0 * 16) = pack2(xa[0], xb[0]);
      *(unsigned*)(fp + 1 * 16) = pack2(xa[1], xb[1]);
      *(unsigned*)(fp + 2 * 16) = pack2(xa[2], xb[2]);
#pragma unroll
      for (int c = 3; c < 8; ++c) *(unsigned*)(fp + c * 16) = 0u;
    }
    __syncthreads();  // (B)
    if (ch < 8) {  // prefetch next chunk's gather
      int nc = ch + 1;
      if (nc < 8) {
        pf0 = *(const uint4*)(ptB + (size_t)ig0 * 64 + nc * 8);
        pf1 = *(const uint4*)(ptB + (size_t)ig1 * 64 + nc * 8);
      }
    }
    // agg via block-diagonal MFMA: 2 s per MFMA, 4 MFMAs per wave
#pragma unroll
    for (int pp = 0; pp < 4; ++pp) {
      int s2 = (wv * 4 + pp) * 2;
      uint4 au = *(const uint4*)(feat2 + s2 * 144 + aoff);
      if (!adiag) au = make_uint4(0u, 0u, 0u, 0u);
      bf16x8 af = __builtin_bit_cast(bf16x8, au);
      bf16x8 bw = *(const bf16x8*)(w_sT + s2 * 264 + boff);
      f32x4 d = __builtin_amdgcn_mfma_f32_16x16x32_bf16(af, bw, zc, 0, 0, 0);
      bf16* cp = aggA + s2 * 136 + soff;
#pragma unroll
      for (int r = 0; r < 4; ++r) cp[r * 16] = (bf16)d[r];
    }
    __syncthreads();  // (C)
    // main GEMM: A from aggA (LDS), B from wlF (global, coalesced 1KB/wave).
    // Wave wv: rows 0..31 (both row-tiles), col tiles {wv, wv+4}.
    {
      const bf16* arow0 = aggA + l16 * 136 + q * 8;
      const bf16* arow1 = aggA + (16 + l16) * 136 + q * 8;
      const size_t lb = (size_t)lane * 8;
      const size_t kb = (size_t)(ch * 4) * 512;
      const bf16* w0f = wlF + (size_t)wv * 17408 + kb + lb;
      const bf16* w1f = wlF + (size_t)(wv + 4) * 17408 + kb + lb;
      for (int kk = 0; kk < nkk; ++kk) {
        bf16x8 af0 = *(const bf16x8*)(arow0 + kk * 32);
        bf16x8 af1 = *(const bf16x8*)(arow1 + kk * 32);
        bf16x8 bf0 = *(const bf16x8*)(w0f + kk * 512);
        bf16x8 bf1 = *(const bf16x8*)(w1f + kk * 512);
        a00 = __builtin_amdgcn_mfma_f32_16x16x32_bf16(af0, bf0, a00, 0, 0, 0);
        a01 = __builtin_amdgcn_mfma_f32_16x16x32_bf16(af0, bf1, a01, 0, 0, 0);
        a10 = __builtin_amdgcn_mfma_f32_16x16x32_bf16(af1, bf0, a10, 0, 0, 0);
        a11 = __builtin_amdgcn_mfma_f32_16x16x32_bf16(af1, bf1, a11, 0, 0, 0);
      }
    }
  }

  __syncthreads();
  // ---- epilogue: +bl, LN(128), *gl+bel, leaky, transposed f32 store ----
  float* out_s = (float*)w_sT;  // [32][132]; w_sT dead now
  {
    // a00: rows q*4+r,   col wv*16+l16;  a01: rows q*4+r,   col 64+wv*16+l16
    // a10: rows 16+q*4+r, same cols.
    int row0 = q * 4;
    int row1 = 16 + q * 4;
    int c0 = wv * 16 + l16;
    int c1 = 64 + c0;
    float bl0 = blp[c0], bl1 = blp[c1];
#pragma unroll
    for (int r = 0; r < 4; ++r) {
      out_s[(row0 + r) * 132 + c0] = a00[r] + bl0;
      out_s[(row0 + r) * 132 + c1] = a01[r] + bl1;
      out_s[(row1 + r) * 132 + c0] = a10[r] + bl0;
      out_s[(row1 + r) * 132 + c1] = a11[r] + bl1;
    }
  }
  __syncthreads();
  {
    int r = tid >> 3, g = tid & 7;
    const float* rowp = out_s + r * 132;
    float s1 = 0.f;
#pragma unroll
    for (int i = 0; i < 16; ++i) s1 += rowp[g + 8 * i];
    s1 += __shfl_xor(s1, 1);
    s1 += __shfl_xor(s1, 2);
    s1 += __shfl_xor(s1, 4);
    float m = s1 * (1.0f / 128.0f);
    float s2 = 0.f;
#pragma unroll
    for (int i = 0; i < 16; ++i) { float d = rowp[g + 8 * i] - m; s2 += d * d; }
    s2 += __shfl_xor(s2, 1);
    s2 += __shfl_xor(s2, 2);
    s2 += __shfl_xor(s2, 4);
    if (g == 0) {
      ln_m[r] = m;
      ln_i[r] = rsqrtf(s2 * (1.0f / 128.0f) + 1e-5f);
    }
  }
  __syncthreads();
  {
    int d = tid >> 1, sh = tid & 1;
    float gld = glp[d], beld = belp[d];
    float vals[16];
#pragma unroll
    for (int j = 0; j < 16; ++j) {
      int r = sh * 16 + j;
      float v = (out_s[r * 132 + d] - ln_m[r]) * ln_i[r] * gld + beld;
      vals[j] = v < 0.f ? 0.2f * v : v;
    }
    float* op = out + ((size_t)b * DOUT + d) * S_ + s0 + sh * 16;
#pragma unroll
    for (int i = 0; i < 4; ++i)
      *(float4*)(op + 4 * i) =
          make_float4(vals[4 * i], vals[4 * i + 1], vals[4 * i + 2], vals[4 * i + 3]);
  }
}

extern "C" void kernel_launch(void* const* d_in, const int* in_sizes, int n_in,
                              void* d_out, int out_size, void* d_ws, size_t ws_size,
                              hipStream_t stream) {
  const float* xyz  = (const float*)d_in[0];
  const float* pts  = (const float*)d_in[1];
  const float* nxyz = (const float*)d_in[2];
  const int* nnidx  = (const int*)d_in[3];
  const float* w0p  = (const float*)d_in[4];
  const float* b0p  = (const float*)d_in[5];
  const float* g0p  = (const float*)d_in[6];
  const float* be0p = (const float*)d_in[7];
  const float* w1p  = (const float*)d_in[8];
  const float* b1p  = (const float*)d_in[9];
  const float* g1p  = (const float*)d_in[10];
  const float* be1p = (const float*)d_in[11];
  const float* w2p  = (const float*)d_in[12];
  const float* b2p  = (const float*)d_in[13];
  const float* g2p  = (const float*)d_in[14];
  const float* be2p = (const float*)d_in[15];
  const float* wlp  = (const float*)d_in[16];
  const float* blp  = (const float*)d_in[17];
  const float* glp  = (const float*)d_in[18];
  const float* belp = (const float*)d_in[19];
  float* out = (float*)d_out;

  const size_t PTT_BYTES = (size_t)B_ * N_ * 64 * 2;       // 33.55 MB
  const size_t WLF_BYTES = (size_t)8 * 34 * 64 * 8 * 2;    // 0.27 MB
  bf16* ptT = (bf16*)d_ws;
  bf16* wlF = (bf16*)((char*)d_ws + PTT_BYTES);

  (void)hipGetLastError();

  if (ws_size < PTT_BYTES + WLF_BYTES) {
    k_fill<<<dim3(8), dim3(256), 0, stream>>>(out, 5000.0f);
    return;
  }

  k_prep<<<dim3(1024 + 8 * 34), dim3(256), 0, stream>>>(pts, ptT, wlp, wlF);
  hipError_t e1 = hipGetLastError();
  k_main<<<dim3(S_ / TS, B_), dim3(256), 0, stream>>>(
      xyz, nxyz, nnidx, ptT, wlF,
      w0p, b0p, g0p, be0p, w1p, b1p, g1p, be1p,
      w2p, b2p, g2p, be2p, blp, glp, belp, out);
  hipError_t e3 = hipGetLastError();

  if (e1 != hipSuccess)
    k_fill<<<dim3(8), dim3(256), 0, stream>>>(out, 2000.0f + (float)(int)e1);
  if (e3 != hipSuccess)
    k_fill<<<dim3(8), dim3(256), 0, stream>>>(out, 4000.0f + (float)(int)e3);
}